// Round 7
// baseline (244.719 us; speedup 1.0000x reference)
//
#include <hip/hip_runtime.h>
#include <hip/hip_bf16.h>

#define B 16
#define S 4096
#define D 256
#define U 256
#define ROWS 64
#define NCHK (S / ROWS)  // 64 chunks per batch

typedef short short8 __attribute__((ext_vector_type(8)));
typedef float f32x4 __attribute__((ext_vector_type(4)));

__device__ __forceinline__ ushort f2bf(float f) {
    union { float f; uint u; } x{f};
    uint r = (x.u + 0x7fffu + ((x.u >> 16) & 1u)) >> 16;  // RNE
    return (ushort)r;
}

__device__ __forceinline__ float fast_tanh(float x) {
    float e = __expf(2.0f * x);
    return 1.0f - 2.0f * __builtin_amdgcn_rcpf(e + 1.0f);
}

// Single fused kernel, 1024 blocks x 256 threads. No cooperative launch:
//  - producer blocks 0..23 (pq GEMV / W1 pack) publish via device-scope counter;
//    they never wait, and are dispatched first -> consumer spin cannot deadlock.
//  - per-batch "last block ticket" finisher replaces the second grid sync.
__global__ void fused_all(
    const float* __restrict__ values, const float* __restrict__ query,
    const float* __restrict__ W1, const float* __restrict__ b1,
    const float* __restrict__ W2, const float* __restrict__ b2,
    const float* __restrict__ V, const float* __restrict__ bV,
    float* __restrict__ pqb, ushort* __restrict__ W1p,
    float* __restrict__ cstats, float* __restrict__ cpart,
    int* __restrict__ syncp, float* __restrict__ wout, float* __restrict__ ctx) {
    __shared__ ushort Alds[ROWS * 256];  // 32 KB, XOR-swizzled bf16 tile
    __shared__ float red[4][ROWS];
    __shared__ float wch[ROWS];
    __shared__ float scl[NCHK];
    __shared__ float stats2[2];
    __shared__ int lastFlag;

    const int bid = blockIdx.x;
    const int t = threadIdx.x;
    const int w = t >> 6, l = t & 63;
    char* lds = (char*)Alds;
    const int b = bid >> 6;
    const int s0 = (bid & 63) * ROWS;

    // ---- producers: blocks 0..15 pq GEMV, 16..23 W1 pack; publish counter ----
    if (bid < 16) {
        const float* qb = query + bid * D;
        float acc = b2[t] + b1[t];
#pragma unroll 8
        for (int d = 0; d < D; ++d)
            acc = fmaf(qb[d], W2[d * U + t], acc);
        pqb[bid * U + t] = acc;
        __syncthreads();
        if (t == 0) {
            __threadfence();
            __hip_atomic_fetch_add(&syncp[0], 1, __ATOMIC_ACQ_REL,
                                   __HIP_MEMORY_SCOPE_AGENT);
        }
    } else if (bid < 24) {
        int kk = bid - 16;
        int colu0 = l & 15;
        int k0 = kk * 32 + (l >> 4) * 8;
#pragma unroll
        for (int i = 0; i < 4; ++i) {
            int nt = w * 4 + i;
            int colu = nt * 16 + colu0;
            ushort* dst = W1p + (((nt * 8) + kk) * 64 + l) * 8;
#pragma unroll
            for (int e = 0; e < 8; ++e) dst[e] = f2bf(W1[(k0 + e) * U + colu]);
        }
        __syncthreads();
        if (t == 0) {
            __threadfence();
            __hip_atomic_fetch_add(&syncp[0], 1, __ATOMIC_ACQ_REL,
                                   __HIP_MEMORY_SCOPE_AGENT);
        }
    }

    // ---- stage 64x256 fp32 -> bf16 LDS, byte ^= (row&7)<<4 (overlaps producers) ----
    const float* src = values + ((size_t)(b * S + s0)) * D;
#pragma unroll
    for (int i = 0; i < 16; ++i) {
        int row = i * 4 + w;
        int col = l * 4;
        float4 v = *(const float4*)&src[row * 256 + col];
        ushort4 h;
        h.x = f2bf(v.x); h.y = f2bf(v.y); h.z = f2bf(v.z); h.w = f2bf(v.w);
        int byte = (row * 512 + col * 2) ^ ((row & 7) << 4);
        *(ushort4*)(lds + byte) = h;
    }

    // ---- wait for producers (t0 spins; producers never wait -> no deadlock) ----
    if (t == 0) {
        while (__hip_atomic_load(&syncp[0], __ATOMIC_ACQUIRE,
                                 __HIP_MEMORY_SCOPE_AGENT) < 24)
            __builtin_amdgcn_s_sleep(2);
    }
    __syncthreads();

    // ---- MFMA scores (round-5-verified math) ----
    const int lrow = l & 15, lk = l >> 4;
    f32x4 acc[4][4];
#pragma unroll
    for (int mt = 0; mt < 4; ++mt)
#pragma unroll
        for (int nt = 0; nt < 4; ++nt) acc[mt][nt] = (f32x4){0.f, 0.f, 0.f, 0.f};

    for (int kk = 0; kk < 8; ++kk) {
        short8 afr[4], bfr[4];
#pragma unroll
        for (int mt = 0; mt < 4; ++mt) {
            int row = mt * 16 + lrow;
            int byte = (row * 512 + kk * 64 + lk * 16) ^ ((row & 7) << 4);
            afr[mt] = *(const short8*)(lds + byte);
        }
#pragma unroll
        for (int nt = 0; nt < 4; ++nt)
            bfr[nt] = *(const short8*)&W1p[((((w * 4 + nt) * 8) + kk) * 64 + l) * 8];
#pragma unroll
        for (int mt = 0; mt < 4; ++mt)
#pragma unroll
            for (int nt = 0; nt < 4; ++nt)
                acc[mt][nt] = __builtin_amdgcn_mfma_f32_16x16x32_bf16(
                    afr[mt], bfr[nt], acc[mt][nt], 0, 0, 0);
    }

    float bb[4], vv[4];
#pragma unroll
    for (int nt = 0; nt < 4; ++nt) {
        int u = (w * 4 + nt) * 16 + lrow;
        bb[nt] = pqb[b * U + u];
        vv[nt] = V[u];
    }
#pragma unroll
    for (int mt = 0; mt < 4; ++mt) {
#pragma unroll
        for (int r = 0; r < 4; ++r) {
            float s = 0.f;
#pragma unroll
            for (int nt = 0; nt < 4; ++nt)
                s += fast_tanh(acc[mt][nt][r] + bb[nt]) * vv[nt];
            s += __shfl_xor(s, 1);
            s += __shfl_xor(s, 2);
            s += __shfl_xor(s, 4);
            s += __shfl_xor(s, 8);
            if (lrow == 0) red[w][mt * 16 + lk * 4 + r] = s;
        }
    }
    __syncthreads();

    if (t < ROWS) {  // wave 0: chunk stats + unnormalized weights -> wout
        float s = red[0][t] + red[1][t] + red[2][t] + red[3][t] + bV[0];
        float m = s;
#pragma unroll
        for (int off = 32; off; off >>= 1) m = fmaxf(m, __shfl_xor(m, off));
        float z0 = __expf(s - m);
        wch[t] = z0;
        wout[b * S + s0 + t] = z0;  // finisher rescales in place
        float z = z0;
#pragma unroll
        for (int off = 32; off; off >>= 1) z += __shfl_xor(z, off);
        if (t == 0) {
            cstats[2 * bid] = m;
            cstats[2 * bid + 1] = z;
        }
    }
    __syncthreads();

    // partial context from bf16 LDS: thread t owns column t (ds_read_u16, conflict-free)
    {
        union { uint i; float f; } cv;
        float cacc = 0.f;
#pragma unroll 8
        for (int r = 0; r < ROWS; ++r) {
            int byte = (r * 512 + t * 2) ^ ((r & 7) << 4);
            ushort u = *(const ushort*)(lds + byte);
            cv.i = (uint)u << 16;
            cacc = fmaf(wch[r], cv.f, cacc);
        }
        cpart[(size_t)bid * D + t] = cacc;
    }

    // ---- last-block ticket per batch ----
    __syncthreads();
    if (t == 0) {
        __threadfence();
        int old = __hip_atomic_fetch_add(&syncp[1 + b], 1, __ATOMIC_ACQ_REL,
                                         __HIP_MEMORY_SCOPE_AGENT);
        lastFlag = (old == NCHK - 1);
    }
    __syncthreads();
    if (!lastFlag) return;

    // ---- finisher for batch b ----
    if (t < NCHK) {
        float m = cstats[2 * (b * NCHK + t)];
        float z = cstats[2 * (b * NCHK + t) + 1];
        float M = m;
#pragma unroll
        for (int off = 32; off; off >>= 1) M = fmaxf(M, __shfl_xor(M, off));
        float zz = z * __expf(m - M);
#pragma unroll
        for (int off = 32; off; off >>= 1) zz += __shfl_xor(zz, off);
        scl[t] = __expf(m - M);
        if (t == 0) { stats2[0] = M; stats2[1] = zz; }
    }
    __syncthreads();
    float invZ = 1.0f / stats2[1];

    // ctx: thread t owns dim t
    float cacc = 0.f;
#pragma unroll 8
    for (int c = 0; c < NCHK; ++c)
        cacc = fmaf(scl[c], cpart[(size_t)(b * NCHK + c) * D + t], cacc);
    ctx[b * D + t] = cacc * invZ;

    // wout rescale in place: 16 per thread
#pragma unroll
    for (int i = 0; i < 16; ++i) {
        int ss = i * 256 + t;
        wout[b * S + ss] *= scl[ss >> 6] * invZ;
    }
}

extern "C" void kernel_launch(void* const* d_in, const int* in_sizes, int n_in,
                              void* d_out, int out_size, void* d_ws, size_t ws_size,
                              hipStream_t stream) {
    const float* values = (const float*)d_in[0];
    const float* query  = (const float*)d_in[1];
    const float* W1     = (const float*)d_in[2];
    const float* b1     = (const float*)d_in[3];
    const float* W2     = (const float*)d_in[4];
    const float* b2     = (const float*)d_in[5];
    const float* V      = (const float*)d_in[6];
    const float* bV     = (const float*)d_in[7];

    float* out  = (float*)d_out;
    float* ctx  = out;          // [B, D]
    float* wout = out + B * D;  // [B, S, 1]

    float* ws     = (float*)d_ws;
    float* pqb    = ws;                 // 4096
    float* cstats = pqb + B * U;        // 2048
    float* cpart  = cstats + 2048;      // 262144
    ushort* W1p   = (ushort*)(cpart + (size_t)B * NCHK * D);  // 65536 ushorts
    int* syncp    = (int*)(W1p + 65536);  // [0]=ready, [1..16]=done tickets

    hipMemsetAsync(syncp, 0, 32 * sizeof(int), stream);
    fused_all<<<B * NCHK, 256, 0, stream>>>(values, query, W1, b1, W2, b2, V, bV,
                                            pqb, W1p, cstats, cpart, syncp, wout, ctx);
}

// Round 8
// 84.439 us; speedup vs baseline: 2.8982x; 2.8982x over previous
//
#include <hip/hip_runtime.h>
#include <hip/hip_bf16.h>

#define B 16
#define S 4096
#define D 256
#define U 256
#define ROWS 64
#define NCHK (S / ROWS)  // 64 chunks per batch

typedef short short8 __attribute__((ext_vector_type(8)));
typedef float f32x4 __attribute__((ext_vector_type(4)));

__device__ __forceinline__ ushort f2bf(float f) {
    union { float f; uint u; } x{f};
    uint r = (x.u + 0x7fffu + ((x.u >> 16) & 1u)) >> 16;  // RNE
    return (ushort)r;
}

__device__ __forceinline__ float fast_tanh(float x) {
    float e = __expf(2.0f * x);
    return 1.0f - 2.0f * __builtin_amdgcn_rcpf(e + 1.0f);
}

// KA: setup. blocks 0..15: pqb GEMV (ILP-restructured); blocks 16..23: W1 pack.
__global__ void ka_setup(const float* __restrict__ query, const float* __restrict__ W2,
                         const float* __restrict__ b2, const float* __restrict__ b1,
                         const float* __restrict__ W1, float* __restrict__ pqb,
                         ushort* __restrict__ W1p) {
    __shared__ float pp[4][U];
    int bid = blockIdx.x, t = threadIdx.x;
    if (bid < 16) {
        // pqb[b][u] = query[b,:].W2[:,u] + b2[u] + b1[u]
        // thread = (dchunk dc 0..3) x (uquad 0..63); 4 consecutive u via float4 row loads
        const float* qb = query + bid * D;
        int u0 = (t & 63) * 4, dc = t >> 6;
        float4 a = {0.f, 0.f, 0.f, 0.f};
#pragma unroll 16
        for (int i = 0; i < 64; ++i) {
            int d = dc * 64 + i;
            float qd = qb[d];
            float4 wv = *(const float4*)&W2[d * U + u0];
            a.x = fmaf(qd, wv.x, a.x);
            a.y = fmaf(qd, wv.y, a.y);
            a.z = fmaf(qd, wv.z, a.z);
            a.w = fmaf(qd, wv.w, a.w);
        }
        *(float4*)&pp[dc][u0] = a;
        __syncthreads();
        pqb[bid * U + t] = pp[0][t] + pp[1][t] + pp[2][t] + pp[3][t] + b2[t] + b1[t];
    } else {
        // pack W1 (fp32 [D][U]) into bf16 MFMA B-fragment order, one kk per block
        int kk = bid - 16;
        int l = t & 63, g = t >> 6;
        int colu0 = l & 15;
        int k0 = kk * 32 + (l >> 4) * 8;
#pragma unroll
        for (int i = 0; i < 4; ++i) {
            int nt = g * 4 + i;
            int colu = nt * 16 + colu0;
            ushort* dst = W1p + (((nt * 8) + kk) * 64 + l) * 8;
#pragma unroll
            for (int e = 0; e < 8; ++e) dst[e] = f2bf(W1[(k0 + e) * U + colu]);
        }
    }
}

// KB: per 64-row chunk: scores via bf16 MFMA, chunk stats, bf16-LDS partial context,
// unnormalized weights -> wout; last block of each batch (ticket) finishes:
// global M,Z; ctx; wout rescale in place.
__global__ void kb_scores(const float* __restrict__ values, const ushort* __restrict__ W1p,
                          const float* __restrict__ pqb, const float* __restrict__ V,
                          const float* __restrict__ bV, float* __restrict__ cstats,
                          float* __restrict__ cpart, int* __restrict__ syncp,
                          float* __restrict__ wout, float* __restrict__ ctx) {
    __shared__ ushort Alds[ROWS * 256];  // 32 KB, XOR-swizzled bf16 tile
    __shared__ float red[4][ROWS];
    __shared__ float wch[ROWS];
    __shared__ float scl[NCHK];
    __shared__ float stats2[2];
    __shared__ int lastFlag;
    const int bid = blockIdx.x;
    const int t = threadIdx.x;
    const int w = t >> 6, l = t & 63;
    char* lds = (char*)Alds;
    const int b = bid >> 6;
    const int s0 = (bid & 63) * ROWS;

    // stage 64x256 fp32 -> bf16 LDS, byte ^= (row&7)<<4
    const float* src = values + ((size_t)(b * S + s0)) * D;
#pragma unroll
    for (int i = 0; i < 16; ++i) {
        int row = i * 4 + w;
        int col = l * 4;
        float4 v = *(const float4*)&src[row * 256 + col];
        ushort4 h;
        h.x = f2bf(v.x); h.y = f2bf(v.y); h.z = f2bf(v.z); h.w = f2bf(v.w);
        int byte = (row * 512 + col * 2) ^ ((row & 7) << 4);
        *(ushort4*)(lds + byte) = h;
    }
    __syncthreads();

    // MFMA scores
    const int lrow = l & 15, lk = l >> 4;
    f32x4 acc[4][4];
#pragma unroll
    for (int mt = 0; mt < 4; ++mt)
#pragma unroll
        for (int nt = 0; nt < 4; ++nt) acc[mt][nt] = (f32x4){0.f, 0.f, 0.f, 0.f};

    for (int kk = 0; kk < 8; ++kk) {
        short8 afr[4], bfr[4];
#pragma unroll
        for (int mt = 0; mt < 4; ++mt) {
            int row = mt * 16 + lrow;
            int byte = (row * 512 + kk * 64 + lk * 16) ^ ((row & 7) << 4);
            afr[mt] = *(const short8*)(lds + byte);
        }
#pragma unroll
        for (int nt = 0; nt < 4; ++nt)
            bfr[nt] = *(const short8*)&W1p[((((w * 4 + nt) * 8) + kk) * 64 + l) * 8];
#pragma unroll
        for (int mt = 0; mt < 4; ++mt)
#pragma unroll
            for (int nt = 0; nt < 4; ++nt)
                acc[mt][nt] = __builtin_amdgcn_mfma_f32_16x16x32_bf16(
                    afr[mt], bfr[nt], acc[mt][nt], 0, 0, 0);
    }

    // epilogue: tanh, .V, reduce over u
    float bb[4], vv[4];
#pragma unroll
    for (int nt = 0; nt < 4; ++nt) {
        int u = (w * 4 + nt) * 16 + lrow;
        bb[nt] = pqb[b * U + u];
        vv[nt] = V[u];
    }
#pragma unroll
    for (int mt = 0; mt < 4; ++mt) {
#pragma unroll
        for (int r = 0; r < 4; ++r) {
            float s = 0.f;
#pragma unroll
            for (int nt = 0; nt < 4; ++nt)
                s += fast_tanh(acc[mt][nt][r] + bb[nt]) * vv[nt];
            s += __shfl_xor(s, 1);
            s += __shfl_xor(s, 2);
            s += __shfl_xor(s, 4);
            s += __shfl_xor(s, 8);
            if (lrow == 0) red[w][mt * 16 + lk * 4 + r] = s;
        }
    }
    __syncthreads();

    if (t < ROWS) {  // wave 0: chunk stats + unnormalized weights -> wout
        float s = red[0][t] + red[1][t] + red[2][t] + red[3][t] + bV[0];
        float m = s;
#pragma unroll
        for (int off = 32; off; off >>= 1) m = fmaxf(m, __shfl_xor(m, off));
        float z0 = __expf(s - m);
        wch[t] = z0;
        wout[b * S + s0 + t] = z0;  // finisher rescales in place
        float z = z0;
#pragma unroll
        for (int off = 32; off; off >>= 1) z += __shfl_xor(z, off);
        if (t == 0) {
            cstats[2 * bid] = m;
            cstats[2 * bid + 1] = z;
        }
    }
    __syncthreads();

    // partial context from bf16 LDS: thread t owns column t (conflict-free u16 reads)
    {
        union { uint i; float f; } cv;
        float cacc = 0.f;
#pragma unroll 8
        for (int r = 0; r < ROWS; ++r) {
            int byte = (r * 512 + t * 2) ^ ((r & 7) << 4);
            ushort u = *(const ushort*)(lds + byte);
            cv.i = (uint)u << 16;
            cacc = fmaf(wch[r], cv.f, cacc);
        }
        cpart[(size_t)bid * D + t] = cacc;
    }

    // last-block ticket per batch (no spinning: only the winner proceeds)
    __syncthreads();
    if (t == 0) {
        __threadfence();
        int old = __hip_atomic_fetch_add(&syncp[b], 1, __ATOMIC_ACQ_REL,
                                         __HIP_MEMORY_SCOPE_AGENT);
        lastFlag = (old == NCHK - 1);
    }
    __syncthreads();
    if (!lastFlag) return;

    // finisher for batch b
    if (t < NCHK) {
        float m = cstats[2 * (b * NCHK + t)];
        float z = cstats[2 * (b * NCHK + t) + 1];
        float M = m;
#pragma unroll
        for (int off = 32; off; off >>= 1) M = fmaxf(M, __shfl_xor(M, off));
        float zz = z * __expf(m - M);
#pragma unroll
        for (int off = 32; off; off >>= 1) zz += __shfl_xor(zz, off);
        scl[t] = __expf(m - M);
        if (t == 0) { stats2[0] = M; stats2[1] = zz; }
    }
    __syncthreads();
    float invZ = 1.0f / stats2[1];

    // ctx: thread t owns dim t
    float cacc = 0.f;
#pragma unroll 8
    for (int c = 0; c < NCHK; ++c)
        cacc = fmaf(scl[c], cpart[(size_t)(b * NCHK + c) * D + t], cacc);
    ctx[b * D + t] = cacc * invZ;

    // wout rescale in place: 16 entries per thread
#pragma unroll
    for (int i = 0; i < 16; ++i) {
        int ss = i * 256 + t;
        wout[b * S + ss] *= scl[ss >> 6] * invZ;
    }
}

extern "C" void kernel_launch(void* const* d_in, const int* in_sizes, int n_in,
                              void* d_out, int out_size, void* d_ws, size_t ws_size,
                              hipStream_t stream) {
    const float* values = (const float*)d_in[0];
    const float* query  = (const float*)d_in[1];
    const float* W1     = (const float*)d_in[2];
    const float* b1     = (const float*)d_in[3];
    const float* W2     = (const float*)d_in[4];
    const float* b2     = (const float*)d_in[5];
    const float* V      = (const float*)d_in[6];
    const float* bV     = (const float*)d_in[7];

    float* out  = (float*)d_out;
    float* ctx  = out;          // [B, D]
    float* wout = out + B * D;  // [B, S, 1]

    float* ws     = (float*)d_ws;
    float* pqb    = ws;                 // 4096
    float* cstats = pqb + B * U;        // 2048
    float* cpart  = cstats + 2048;      // B*NCHK*D = 262144
    ushort* W1p   = (ushort*)(cpart + (size_t)B * NCHK * D);  // 65536 ushorts
    int* syncp    = (int*)(W1p + 65536);  // [0..15] per-batch tickets

    hipMemsetAsync(syncp, 0, 16 * sizeof(int), stream);
    ka_setup<<<24, 256, 0, stream>>>(query, W2, b2, b1, W1, pqb, W1p);
    kb_scores<<<B * NCHK, 256, 0, stream>>>(values, W1p, pqb, V, bV,
                                            cstats, cpart, syncp, wout, ctx);
}

// Round 9
// 46.701 us; speedup vs baseline: 5.2402x; 1.8081x over previous
//
#include <hip/hip_runtime.h>
#include <hip/hip_bf16.h>

#define B 16
#define S 4096
#define D 256
#define U 256
#define ROWS 64
#define NCHK (S / ROWS)  // 64 chunks per batch

typedef short short8 __attribute__((ext_vector_type(8)));
typedef float f32x4 __attribute__((ext_vector_type(4)));

__device__ __forceinline__ ushort f2bf(float f) {
    union { float f; uint u; } x{f};
    uint r = (x.u + 0x7fffu + ((x.u >> 16) & 1u)) >> 16;  // RNE
    return (ushort)r;
}

__device__ __forceinline__ float fast_tanh(float x) {
    float e = __expf(2.0f * x);
    return 1.0f - 2.0f * __builtin_amdgcn_rcpf(e + 1.0f);
}

// KA: setup. blocks 0..15: pqb GEMV (ILP-parallel); blocks 16..23: W1 pack.
__global__ void ka_setup(const float* __restrict__ query, const float* __restrict__ W2,
                         const float* __restrict__ b2, const float* __restrict__ b1,
                         const float* __restrict__ W1, float* __restrict__ pqb,
                         ushort* __restrict__ W1p) {
    __shared__ float pp[4][U];
    int bid = blockIdx.x, t = threadIdx.x;
    if (bid < 16) {
        // pqb[b][u] = query[b,:].W2[:,u] + b2[u] + b1[u]
        const float* qb = query + bid * D;
        int u0 = (t & 63) * 4, dc = t >> 6;
        float4 a = {0.f, 0.f, 0.f, 0.f};
#pragma unroll 16
        for (int i = 0; i < 64; ++i) {
            int d = dc * 64 + i;
            float qd = qb[d];
            float4 wv = *(const float4*)&W2[d * U + u0];
            a.x = fmaf(qd, wv.x, a.x);
            a.y = fmaf(qd, wv.y, a.y);
            a.z = fmaf(qd, wv.z, a.z);
            a.w = fmaf(qd, wv.w, a.w);
        }
        *(float4*)&pp[dc][u0] = a;
        __syncthreads();
        pqb[bid * U + t] = pp[0][t] + pp[1][t] + pp[2][t] + pp[3][t] + b2[t] + b1[t];
    } else {
        // pack W1 (fp32 [D][U]) into bf16 MFMA B-fragment order, one kk per block
        int kk = bid - 16;
        int l = t & 63, g = t >> 6;
        int colu0 = l & 15;
        int k0 = kk * 32 + (l >> 4) * 8;
#pragma unroll
        for (int i = 0; i < 4; ++i) {
            int nt = g * 4 + i;
            int colu = nt * 16 + colu0;
            ushort* dst = W1p + (((nt * 8) + kk) * 64 + l) * 8;
#pragma unroll
            for (int e = 0; e < 8; ++e) dst[e] = f2bf(W1[(k0 + e) * U + colu]);
        }
    }
}

// KB: per 64-row chunk: scores via bf16 MFMA, chunk softmax stats (m_c, z_c),
// unnormalized weights z0 -> wout, bf16-LDS partial context -> cpart.
// NO fences/atomics — the launch boundary is the grid-wide sync.
__global__ void kb_scores(const float* __restrict__ values, const ushort* __restrict__ W1p,
                          const float* __restrict__ pqb, const float* __restrict__ V,
                          const float* __restrict__ bV, float* __restrict__ cstats,
                          float* __restrict__ cpart, float* __restrict__ wout) {
    __shared__ ushort Alds[ROWS * 256];  // 32 KB, XOR-swizzled bf16 tile
    __shared__ float red[4][ROWS];
    __shared__ float wch[ROWS];
    const int bid = blockIdx.x;
    const int t = threadIdx.x;
    const int w = t >> 6, l = t & 63;
    char* lds = (char*)Alds;
    const int b = bid >> 6;
    const int s0 = (bid & 63) * ROWS;

    // stage 64x256 fp32 -> bf16 LDS, byte ^= (row&7)<<4
    const float* src = values + ((size_t)(b * S + s0)) * D;
#pragma unroll
    for (int i = 0; i < 16; ++i) {
        int row = i * 4 + w;
        int col = l * 4;
        float4 v = *(const float4*)&src[row * 256 + col];
        ushort4 h;
        h.x = f2bf(v.x); h.y = f2bf(v.y); h.z = f2bf(v.z); h.w = f2bf(v.w);
        int byte = (row * 512 + col * 2) ^ ((row & 7) << 4);
        *(ushort4*)(lds + byte) = h;
    }
    __syncthreads();

    // MFMA scores
    const int lrow = l & 15, lk = l >> 4;
    f32x4 acc[4][4];
#pragma unroll
    for (int mt = 0; mt < 4; ++mt)
#pragma unroll
        for (int nt = 0; nt < 4; ++nt) acc[mt][nt] = (f32x4){0.f, 0.f, 0.f, 0.f};

    for (int kk = 0; kk < 8; ++kk) {
        short8 afr[4], bfr[4];
#pragma unroll
        for (int mt = 0; mt < 4; ++mt) {
            int row = mt * 16 + lrow;
            int byte = (row * 512 + kk * 64 + lk * 16) ^ ((row & 7) << 4);
            afr[mt] = *(const short8*)(lds + byte);
        }
#pragma unroll
        for (int nt = 0; nt < 4; ++nt)
            bfr[nt] = *(const short8*)&W1p[((((w * 4 + nt) * 8) + kk) * 64 + l) * 8];
#pragma unroll
        for (int mt = 0; mt < 4; ++mt)
#pragma unroll
            for (int nt = 0; nt < 4; ++nt)
                acc[mt][nt] = __builtin_amdgcn_mfma_f32_16x16x32_bf16(
                    afr[mt], bfr[nt], acc[mt][nt], 0, 0, 0);
    }

    // epilogue: tanh, .V, reduce over u
    float bb[4], vv[4];
#pragma unroll
    for (int nt = 0; nt < 4; ++nt) {
        int u = (w * 4 + nt) * 16 + lrow;
        bb[nt] = pqb[b * U + u];
        vv[nt] = V[u];
    }
#pragma unroll
    for (int mt = 0; mt < 4; ++mt) {
#pragma unroll
        for (int r = 0; r < 4; ++r) {
            float s = 0.f;
#pragma unroll
            for (int nt = 0; nt < 4; ++nt)
                s += fast_tanh(acc[mt][nt][r] + bb[nt]) * vv[nt];
            s += __shfl_xor(s, 1);
            s += __shfl_xor(s, 2);
            s += __shfl_xor(s, 4);
            s += __shfl_xor(s, 8);
            if (lrow == 0) red[w][mt * 16 + lk * 4 + r] = s;
        }
    }
    __syncthreads();

    if (t < ROWS) {  // wave 0: chunk stats + unnormalized weights -> wout
        float s = red[0][t] + red[1][t] + red[2][t] + red[3][t] + bV[0];
        float m = s;
#pragma unroll
        for (int off = 32; off; off >>= 1) m = fmaxf(m, __shfl_xor(m, off));
        float z0 = __expf(s - m);
        wch[t] = z0;
        wout[b * S + s0 + t] = z0;  // KC rescales in place
        float z = z0;
#pragma unroll
        for (int off = 32; off; off >>= 1) z += __shfl_xor(z, off);
        if (t == 0) {
            cstats[2 * bid] = m;
            cstats[2 * bid + 1] = z;
        }
    }
    __syncthreads();

    // partial context from bf16 LDS: thread t owns column t (conflict-free u16 reads)
    union { uint i; float f; } cv;
    float cacc = 0.f;
#pragma unroll 8
    for (int r = 0; r < ROWS; ++r) {
        int byte = (r * 512 + t * 2) ^ ((r & 7) << 4);
        ushort u = *(const ushort*)(lds + byte);
        cv.i = (uint)u << 16;
        cacc = fmaf(wch[r], cv.f, cacc);
    }
    cpart[(size_t)bid * D + t] = cacc;
}

// KC: finisher, block = (batch b, quarter q).
//  - reduce 64 chunk stats -> M, Z (redundant per block)
//  - ctx[b][q*64+dl] = sum_c scl[c] * cpart[c][d] / Z
//  - wout[b][q*1024 .. +1024) *= scl[chunk] / Z   (in-place rescale)
__global__ void kc_final(const float* __restrict__ cstats, const float* __restrict__ cpart,
                         float* __restrict__ wout, float* __restrict__ ctx) {
    __shared__ float scl[NCHK];
    __shared__ float stats2[2];
    __shared__ float part[4][64];
    int b = blockIdx.x >> 2, q = blockIdx.x & 3;
    int t = threadIdx.x;

    if (t < NCHK) {
        float m = cstats[2 * (b * NCHK + t)];
        float z = cstats[2 * (b * NCHK + t) + 1];
        float M = m;
#pragma unroll
        for (int off = 32; off; off >>= 1) M = fmaxf(M, __shfl_xor(M, off));
        float zz = z * __expf(m - M);
#pragma unroll
        for (int off = 32; off; off >>= 1) zz += __shfl_xor(zz, off);
        scl[t] = __expf(m - M);
        if (t == 0) { stats2[0] = M; stats2[1] = zz; }
    }
    __syncthreads();
    float invZ = 1.0f / stats2[1];

    int tq = t >> 6, dl = t & 63;
    int d = q * 64 + dl;
    float acc = 0.f;
#pragma unroll
    for (int i = 0; i < 16; ++i) {
        int c = tq * 16 + i;
        acc = fmaf(scl[c], cpart[(size_t)(b * NCHK + c) * D + d], acc);
    }
    part[tq][dl] = acc;

#pragma unroll
    for (int i = 0; i < 4; ++i) {
        int ss = q * 1024 + i * 256 + t;
        wout[b * S + ss] *= scl[ss >> 6] * invZ;
    }
    __syncthreads();
    if (t < 64)
        ctx[b * D + q * 64 + t] =
            (part[0][t] + part[1][t] + part[2][t] + part[3][t]) * invZ;
}

extern "C" void kernel_launch(void* const* d_in, const int* in_sizes, int n_in,
                              void* d_out, int out_size, void* d_ws, size_t ws_size,
                              hipStream_t stream) {
    const float* values = (const float*)d_in[0];
    const float* query  = (const float*)d_in[1];
    const float* W1     = (const float*)d_in[2];
    const float* b1     = (const float*)d_in[3];
    const float* W2     = (const float*)d_in[4];
    const float* b2     = (const float*)d_in[5];
    const float* V      = (const float*)d_in[6];
    const float* bV     = (const float*)d_in[7];

    float* out  = (float*)d_out;
    float* ctx  = out;          // [B, D]
    float* wout = out + B * D;  // [B, S, 1]

    float* ws     = (float*)d_ws;
    float* pqb    = ws;                 // 4096
    float* cstats = pqb + B * U;        // 2048
    float* cpart  = cstats + 2048;      // B*NCHK*D = 262144
    ushort* W1p   = (ushort*)(cpart + (size_t)B * NCHK * D);  // 65536 ushorts

    ka_setup<<<24, 256, 0, stream>>>(query, W2, b2, b1, W1, pqb, W1p);
    kb_scores<<<B * NCHK, 256, 0, stream>>>(values, W1p, pqb, V, bV,
                                            cstats, cpart, wout);
    kc_final<<<B * 4, 256, 0, stream>>>(cstats, cpart, wout, ctx);
}